// Round 7
// baseline (1172.732 us; speedup 1.0000x reference)
//
#include <hip/hip_runtime.h>

// B=4096, T=512, IN=32, H=[64,64,128], OUT=10
// 256 blocks x 512 threads (8 waves, 2/SIMD). Wave-specialized software pipeline:
//   waves 0-3 (G01): layer0(t) | layer1(t)
//   waves 4-7 (G23): layer2(t-1) MFMA | layer2(t-1) activations   (one step behind)
// Weights in registers via SHARED array WR[32] (union across groups, 128 regs);
// Wih2 in LDS. h states double-buffered in LDS. ALL MFMAs are builtins (compiler
// handles hazards — R4/R6 showed inline-asm MFMA hazards are not controllable).
// KEY FIX vs R3: __launch_bounds__(512, 1). R3 used (512,2) which HIP reads as
// min 2 BLOCKS/CU -> 4 waves/SIMD -> 128-reg cap -> ~45 regs spilled to scratch
// (24 MB/launch WRITE_SIZE). With 1 block/CU: 2 waves/SIMD -> 256-reg budget,
// static demand ~235 (G23) / ~195 (G01) fits -> no spills.

using f32x4  = __attribute__((ext_vector_type(4))) float;
using bf16x8 = __attribute__((ext_vector_type(8))) __bf16;

__device__ __forceinline__ __bf16 f2bf(float f) {
  unsigned u = __builtin_bit_cast(unsigned, f);
  unsigned short s = (unsigned short)((u + 0x7fffu + ((u >> 16) & 1u)) >> 16);
  return __builtin_bit_cast(__bf16, s);
}
__device__ __forceinline__ float bf2f(__bf16 b) {
  unsigned short s = __builtin_bit_cast(unsigned short, b);
  unsigned u = ((unsigned)s) << 16;
  return __builtin_bit_cast(float, u);
}
__device__ __forceinline__ float fsig(float x) {
  return __builtin_amdgcn_rcpf(1.0f + __builtin_amdgcn_exp2f(-1.442695041f * x));
}
__device__ __forceinline__ float ftanh(float x) {
  return 2.0f * __builtin_amdgcn_rcpf(1.0f + __builtin_amdgcn_exp2f(-2.885390082f * x)) - 1.0f;
}

#define MF(A, Bv, C) __builtin_amdgcn_mfma_f32_16x16x32_bf16((A), (Bv), (C), 0, 0, 0)

__device__ __forceinline__ bf16x8 ldw8(const float* p) {
  float4 v0 = *(const float4*)p;
  float4 v1 = *(const float4*)(p + 4);
  bf16x8 r;
  r[0] = f2bf(v0.x); r[1] = f2bf(v0.y); r[2] = f2bf(v0.z); r[3] = f2bf(v0.w);
  r[4] = f2bf(v1.x); r[5] = f2bf(v1.y); r[6] = f2bf(v1.z); r[7] = f2bf(v1.w);
  return r;
}

__global__ __launch_bounds__(512, 1)
void lstm_kernel(const float* __restrict__ x,
                 const float* __restrict__ Wih0, const float* __restrict__ Whh0,
                 const float* __restrict__ bih0, const float* __restrict__ bhh0,
                 const float* __restrict__ Wih1, const float* __restrict__ Whh1,
                 const float* __restrict__ bih1, const float* __restrict__ bhh1,
                 const float* __restrict__ Wih2, const float* __restrict__ Whh2,
                 const float* __restrict__ bih2, const float* __restrict__ bhh2,
                 const float* __restrict__ Wfc, const float* __restrict__ bfc,
                 float* __restrict__ out) {
  // double-buffered h states (stride 72/136 shorts -> 2-way bank aliasing only, free)
  __shared__ __align__(16) __bf16 h0s[2][16][72];
  __shared__ __align__(16) __bf16 h1s[2][16][72];
  __shared__ __align__(16) __bf16 h2s[2][16][136];
  // Wih2 staged in LDS [512][72] (row pad 8 -> 2-way aliasing only)
  __shared__ __align__(16) __bf16 wih2l[512][72];

  const int tid = threadIdx.x;
  const int w   = tid >> 6;      // wave 0..7
  const bool g01 = (w < 4);
  const int gw  = w & 3;         // wave id within group, 0..3
  const int l   = tid & 63;
  const int l15 = l & 15;
  const int lg  = l >> 4;
  const int k0  = lg * 8;
  const int r0  = blockIdx.x << 4;

  for (int i = tid; i < 2 * 16 * 72; i += 512) {
    (&h0s[0][0][0])[i] = __bf16(0.f);
    (&h1s[0][0][0])[i] = __bf16(0.f);
  }
  for (int i = tid; i < 2 * 16 * 136; i += 512) (&h2s[0][0][0])[i] = __bf16(0.f);
  for (int i = tid; i < 512 * 64; i += 512) {
    int row = i >> 6, col = i & 63;
    wih2l[row][col] = f2bf(Wih2[i]);
  }

  // ---- SHARED register arrays: allocation is the union across both groups ----
  // G01: WR[0..3]=Wih0, WR[4..11]=Whh0, WR[12..19]=Wih1, WR[20..27]=Whh1
  // G23: WR[0..31]=Whh2 (s,gi,kk -> 16s+4gi+kk)
  bf16x8 WR[32];
  f32x4  AC[8];     // G01: AC[0..3] reused l0 then l1; G23: AC[4s+gi], live across B1
  float  BI[8];     // G01: bias0[gi], bias1[4+gi]; G23: bias2 -> 4s+gi
  float  CS[8];     // G01: c0[j], c1[4+j]; G23: c2 -> 4s+j
#pragma unroll
  for (int i = 0; i < 8; ++i) CS[i] = 0.f;

  if (g01) {
#pragma unroll
    for (int gi = 0; gi < 4; ++gi) {
      const int row = 16 * (4 * gi + gw) + l15;
      WR[gi] = ldw8(Wih0 + (size_t)row * 32 + k0);
#pragma unroll
      for (int kb = 0; kb < 2; ++kb) {
        WR[4 + 2 * gi + kb]  = ldw8(Whh0 + (size_t)row * 64 + kb * 32 + k0);
        WR[12 + 2 * gi + kb] = ldw8(Wih1 + (size_t)row * 64 + kb * 32 + k0);
        WR[20 + 2 * gi + kb] = ldw8(Whh1 + (size_t)row * 64 + kb * 32 + k0);
      }
      const int c01 = 64 * gi + 16 * gw + l15;
      BI[gi]     = bih0[c01] + bhh0[c01];
      BI[4 + gi] = bih1[c01] + bhh1[c01];
    }
  } else {
#pragma unroll
    for (int s = 0; s < 2; ++s)
#pragma unroll
      for (int gi = 0; gi < 4; ++gi) {
        const int row = 16 * (8 * gi + 2 * gw + s) + l15;
#pragma unroll
        for (int kk = 0; kk < 4; ++kk)
          WR[16 * s + 4 * gi + kk] = ldw8(Whh2 + (size_t)row * 128 + kk * 32 + k0);
        const int c2 = 128 * gi + 32 * gw + 16 * s + l15;
        BI[4 * s + gi] = bih2[c2] + bhh2[c2];
      }
  }

  const float* xrow = x + (size_t)(r0 + l15) * 512 * 32 + k0;
  float4 nx0 = {0.f, 0.f, 0.f, 0.f}, nx1 = {0.f, 0.f, 0.f, 0.f};
  if (g01) { nx0 = *(const float4*)xrow; nx1 = *(const float4*)(xrow + 4); }

  __syncthreads();

#pragma unroll 1
  for (int t = 0; t <= 512; ++t) {
    const int pb = t & 1, rb = pb ^ 1;

    // ---------------- slot 1 ----------------
    if (g01) {
      if (t < 512) {
        // layer0(t): h0(t) = cell(x(t), h0(t-1))
        float4 cx0 = nx0, cx1 = nx1;
        const int tn = (t + 1) & 511;  // wraparound dummy at t=511
        nx0 = *(const float4*)(xrow + (size_t)tn * 32);
        nx1 = *(const float4*)(xrow + (size_t)tn * 32 + 4);

        bf16x8 ax;
        ax[0] = f2bf(cx0.x); ax[1] = f2bf(cx0.y); ax[2] = f2bf(cx0.z); ax[3] = f2bf(cx0.w);
        ax[4] = f2bf(cx1.x); ax[5] = f2bf(cx1.y); ax[6] = f2bf(cx1.z); ax[7] = f2bf(cx1.w);

        bf16x8 a0 = *(const bf16x8*)&h0s[rb][l15][k0];
        bf16x8 a1 = *(const bf16x8*)&h0s[rb][l15][32 + k0];
#pragma unroll
        for (int gi = 0; gi < 4; ++gi) {
          f32x4 a = {BI[gi], BI[gi], BI[gi], BI[gi]};
          a = MF(ax, WR[gi], a);
          a = MF(a0, WR[4 + 2 * gi], a);
          a = MF(a1, WR[5 + 2 * gi], a);
          AC[gi] = a;
        }
#pragma unroll
        for (int j = 0; j < 4; ++j) {
          float nc = fsig(AC[1][j]) * CS[j] + fsig(AC[0][j]) * ftanh(AC[2][j]);
          CS[j] = nc;
          h0s[pb][4 * lg + j][16 * gw + l15] = f2bf(fsig(AC[3][j]) * ftanh(nc));
        }
      }
    } else {
      if (t >= 1) {
        // layer2(t-1) MFMA: gates = Wih2*h1(t-1) + Whh2*h2(t-2) + b
        bf16x8 b0 = *(const bf16x8*)&h1s[rb][l15][k0];
        bf16x8 b1 = *(const bf16x8*)&h1s[rb][l15][32 + k0];
        bf16x8 d0 = *(const bf16x8*)&h2s[pb][l15][k0];
        bf16x8 d1 = *(const bf16x8*)&h2s[pb][l15][32 + k0];
        bf16x8 d2 = *(const bf16x8*)&h2s[pb][l15][64 + k0];
        bf16x8 d3 = *(const bf16x8*)&h2s[pb][l15][96 + k0];
#pragma unroll
        for (int s = 0; s < 2; ++s)
#pragma unroll
          for (int gi = 0; gi < 4; ++gi) {
            const int tile = 8 * gi + 2 * gw + s;
            bf16x8 wa0 = *(const bf16x8*)&wih2l[16 * tile + l15][k0];
            bf16x8 wa1 = *(const bf16x8*)&wih2l[16 * tile + l15][32 + k0];
            f32x4 a = {BI[4 * s + gi], BI[4 * s + gi], BI[4 * s + gi], BI[4 * s + gi]};
            a = MF(b0, wa0, a);
            a = MF(b1, wa1, a);
            a = MF(d0, WR[16 * s + 4 * gi + 0], a);
            a = MF(d1, WR[16 * s + 4 * gi + 1], a);
            a = MF(d2, WR[16 * s + 4 * gi + 2], a);
            a = MF(d3, WR[16 * s + 4 * gi + 3], a);
            AC[4 * s + gi] = a;
          }
      }
    }
    __syncthreads();  // B1: h0(t) visible to G01-l1

    // ---------------- slot 2 ----------------
    if (g01) {
      if (t < 512) {
        // layer1(t): h1(t) = cell(h0(t), h1(t-1))
        bf16x8 a0 = *(const bf16x8*)&h0s[pb][l15][k0];
        bf16x8 a1 = *(const bf16x8*)&h0s[pb][l15][32 + k0];
        bf16x8 b0 = *(const bf16x8*)&h1s[rb][l15][k0];
        bf16x8 b1 = *(const bf16x8*)&h1s[rb][l15][32 + k0];
#pragma unroll
        for (int gi = 0; gi < 4; ++gi) {
          f32x4 a = {BI[4 + gi], BI[4 + gi], BI[4 + gi], BI[4 + gi]};
          a = MF(a0, WR[12 + 2 * gi], a);
          a = MF(a1, WR[13 + 2 * gi], a);
          a = MF(b0, WR[20 + 2 * gi], a);
          a = MF(b1, WR[21 + 2 * gi], a);
          AC[gi] = a;
        }
#pragma unroll
        for (int j = 0; j < 4; ++j) {
          float nc = fsig(AC[1][j]) * CS[4 + j] + fsig(AC[0][j]) * ftanh(AC[2][j]);
          CS[4 + j] = nc;
          h1s[pb][4 * lg + j][16 * gw + l15] = f2bf(fsig(AC[3][j]) * ftanh(nc));
        }
      }
    } else {
      if (t >= 1) {
        // layer2(t-1) activations -> h2(t-1)
#pragma unroll
        for (int s = 0; s < 2; ++s)
#pragma unroll
          for (int j = 0; j < 4; ++j) {
            float nc = fsig(AC[4 * s + 1][j]) * CS[4 * s + j]
                     + fsig(AC[4 * s + 0][j]) * ftanh(AC[4 * s + 2][j]);
            CS[4 * s + j] = nc;
            h2s[rb][4 * lg + j][32 * gw + 16 * s + l15] = f2bf(fsig(AC[4 * s + 3][j]) * ftanh(nc));
          }
      }
    }
    __syncthreads();  // B2: h1(t), h2(t-1) visible
  }

  // ---- final FC: out = h2(511) @ Wfc^T + bfc;  h2(511) is in buffer 1 ----
  if (tid < 160) {
    const int r = tid / 10, o = tid - r * 10;
    float sum = bfc[o];
    for (int u = 0; u < 128; ++u) sum += bf2f(h2s[1][r][u]) * Wfc[o * 128 + u];
    out[(size_t)(r0 + r) * 10 + o] = sum;
  }
}

extern "C" void kernel_launch(void* const* d_in, const int* in_sizes, int n_in,
                              void* d_out, int out_size, void* d_ws, size_t ws_size,
                              hipStream_t stream) {
  const float* x    = (const float*)d_in[0];
  const float* Wih0 = (const float*)d_in[1];
  const float* Whh0 = (const float*)d_in[2];
  const float* bih0 = (const float*)d_in[3];
  const float* bhh0 = (const float*)d_in[4];
  const float* Wih1 = (const float*)d_in[5];
  const float* Whh1 = (const float*)d_in[6];
  const float* bih1 = (const float*)d_in[7];
  const float* bhh1 = (const float*)d_in[8];
  const float* Wih2 = (const float*)d_in[9];
  const float* Whh2 = (const float*)d_in[10];
  const float* bih2 = (const float*)d_in[11];
  const float* bhh2 = (const float*)d_in[12];
  const float* Wfc  = (const float*)d_in[13];
  const float* bfc  = (const float*)d_in[14];

  lstm_kernel<<<256, 512, 0, stream>>>(x, Wih0, Whh0, bih0, bhh0,
                                       Wih1, Whh1, bih1, bhh1,
                                       Wih2, Whh2, bih2, bhh2,
                                       Wfc, bfc, (float*)d_out);
}